// Round 15
// baseline (257.783 us; speedup 1.0000x reference)
//
#include <hip/hip_runtime.h>
#include <stdint.h>

// Problem constants (B, LQ, LK, D fixed by the reference)
#define NB    32
#define SLQ   2048
#define SLK   2048
#define DD    128
#define QTILE 256          // q rows per workgroup (8 waves x 32)
#define KVB   64           // keys per tile
#define NKB   (SLK / KVB)  // 32
#define TILEB 16384        // bytes per K or V^T bf16 tile image (64x128x2)
#define TILES (KVB * DD)   // shorts per tile

typedef __attribute__((ext_vector_type(8)))  short    bf16x8;
typedef __attribute__((ext_vector_type(16))) float    f32x16;
typedef __attribute__((ext_vector_type(4)))  float    f32x4v;
typedef __attribute__((ext_vector_type(4)))  uint32_t u32x4;
typedef __attribute__((ext_vector_type(2)))  uint32_t u32x2;

union FragU { uint32_t u[4]; bf16x8 v; };

__device__ __forceinline__ uint32_t cvtpk(float lo, float hi) {
    uint32_t r;
    asm("v_cvt_pk_bf16_f32 %0, %1, %2" : "=v"(r) : "v"(lo), "v"(hi));
    return r;
}
__device__ __forceinline__ void perm32swap(uint32_t& a, uint32_t& b) {
    asm("v_permlane32_swap_b32 %0, %1" : "+v"(a), "+v"(b));
}
__device__ __forceinline__ uint32_t pack16(u32x4 a) {
    uint32_t r0 = (((a.x & 0x01010101u) * 0x01020408u) >> 24) & 0xFu;
    uint32_t r1 = (((a.y & 0x01010101u) * 0x01020408u) >> 24) & 0xFu;
    uint32_t r2 = (((a.z & 0x01010101u) * 0x01020408u) >> 24) & 0xFu;
    uint32_t r3 = (((a.w & 0x01010101u) * 0x01020408u) >> 24) & 0xFu;
    return r0 | (r1 << 4) | (r2 << 8) | (r3 << 12);
}
#if __has_builtin(__builtin_amdgcn_exp2f)
#define EXP2(x) __builtin_amdgcn_exp2f(x)
#else
#define EXP2(x) exp2f(x)
#endif

// LDS-only barrier (no vmcnt drain); rule #18 fences on both sides.
__device__ __forceinline__ void barrier_lgkm() {
    __builtin_amdgcn_sched_barrier(0);
    asm volatile("s_waitcnt lgkmcnt(0)\n\ts_barrier" ::: "memory");
    __builtin_amdgcn_sched_barrier(0);
}

// ---------------------------------------------------------------------------
// prep_k / prep_v / prep_m: identical to R14 (validated). bf16 tile images
// with LDS swizzle pre-applied + 1-bit mask pack.
// ---------------------------------------------------------------------------
__global__ __launch_bounds__(256, 8)
void prep_k(const float* __restrict__ kp, char* __restrict__ kimg)
{
    const int t  = blockIdx.x * 256 + threadIdx.x;
    const int c  = t & 31;
    const int kk = (t >> 5) & 63;
    const int kb = (t >> 11) & 31;
    const int b  = t >> 16;
    const float* src = kp + ((size_t)b * SLK + (size_t)(kb * KVB + kk)) * DD + 4 * c;
    f32x4v x = *(const f32x4v*)src;
    u32x2 w; w.x = cvtpk(x.x, x.y); w.y = cvtpk(x.z, x.w);
    char* dst = kimg + (size_t)(b * NKB + kb) * TILEB + kk * 256 + ((8 * c) ^ ((kk & 7) << 4));
    *(u32x2*)dst = w;
}

__global__ __launch_bounds__(256, 8)
void prep_v(const float* __restrict__ vp, char* __restrict__ vimg)
{
    const int t  = blockIdx.x * 256 + threadIdx.x;
    const int d  = t & 127;
    const int c  = (t >> 7) & 15;
    const int kb = (t >> 11) & 31;
    const int b  = t >> 16;
    const float* src = vp + ((size_t)b * SLK + (size_t)(kb * KVB + 4 * c)) * DD + d;
    const float a0 = src[0], a1 = src[DD], a2 = src[2 * DD], a3 = src[3 * DD];
    u32x2 w; w.x = cvtpk(a0, a1); w.y = cvtpk(a2, a3);
    char* dst = vimg + (size_t)(b * NKB + kb) * TILEB + d * 128 + ((8 * c) ^ ((d & 15) << 3));
    *(u32x2*)dst = w;
}

__global__ __launch_bounds__(256, 8)
void prep_m(const void* __restrict__ mp, uint32_t* __restrict__ mbits)
{
    __shared__ int det_flags;
    if (threadIdx.x == 0) det_flags = 0;
    __syncthreads();
    {
        const u32x4 w = *(const u32x4*)((const char*)mp + threadIdx.x * 16);
        const uint32_t any_hi    = (w.x | w.y | w.z | w.w) & 0xFFFFFF00u;
        const uint32_t any_mod84 = (w.y | w.w) & 0xFFu;
        const int f = (any_hi ? 1 : 0) | (any_mod84 ? 2 : 0);
        if (f) atomicOr(&det_flags, f);
    }
    __syncthreads();
    const int mflags = det_flags;
    const int mmode  = (mflags & 1) ? 0 : ((mflags & 2) ? 1 : 2);

    const int t   = blockIdx.x * 256 + threadIdx.x;
    const int k32 = t & 63;
    const int q   = (t >> 6) & 2047;
    const int b   = t >> 17;
    const size_t e0 = ((size_t)b * SLQ + q) * SLK + (size_t)k32 * 32;
    uint32_t bits;
    if (mmode == 0) {
        const uint8_t* src = (const uint8_t*)mp + e0;
        u32x4 a = *(const u32x4*)(src);
        u32x4 c = *(const u32x4*)(src + 16);
        bits = pack16(a) | (pack16(c) << 16);
    } else if (mmode == 1) {
        const uint32_t* s = (const uint32_t*)mp + e0;
        bits = 0;
        for (int j = 0; j < 32; ++j) bits |= (s[j] ? 1u : 0u) << j;
    } else {
        const uint64_t* s = (const uint64_t*)mp + e0;
        bits = 0;
        for (int j = 0; j < 32; ++j) bits |= (s[j] ? 1u : 0u) << j;
    }
    mbits[((size_t)b * SLQ + q) * 64 + k32] = bits;
}

// ---------------------------------------------------------------------------
// Main kernel: software-pipelined skew. Region t = {QK^T(t+1) || SM(t) ||
// PV(t)} in ONE scheduling block; 3-buffer LDS rotation; DMA at distance 3
// with counted vmcnt(6). 512 threads, 8 waves, QTILE=256, 1 block/CU.
// ---------------------------------------------------------------------------
__global__ __launch_bounds__(512, 2)
void attn_main(const float* __restrict__ qp, const char* __restrict__ kimg,
               const char* __restrict__ vimg, const uint32_t* __restrict__ mbits,
               float* __restrict__ op)
{
    __shared__ short k_lds[3][TILES];    // 48 KB, image order (pre-swizzled)
    __shared__ short vt_lds[3][TILES];   // 48 KB

    const int tid  = threadIdx.x;
    const int lane = tid & 63;
    const int wv   = tid >> 6;   // wave 0..7, owns q rows [q0+32*wv, +32)
    const int l31  = lane & 31;
    const int hi2  = lane >> 5;  // 0/1

    // XCD-chunked swizzle: 256 WGs -> 32 consecutive work ids per XCD
    const int bid = blockIdx.x;
    const int wg  = (bid & 7) * 32 + (bid >> 3);
    const int b   = wg >> 3;            // batch
    const int q0  = (wg & 7) * QTILE;   // q tile origin

    const float qsc = 0.12751744846458246f;  // log2(e)/sqrt(128)

    // ---- persistent Q fragments (B-operand of swapped QK^T) ----
    bf16x8 qf[8];
    {
        const float* qrow = qp + ((size_t)b * SLQ + (size_t)(q0 + wv * 32 + l31)) * DD;
        #pragma unroll
        for (int ks = 0; ks < 8; ++ks) {
            f32x4v x0 = *(const f32x4v*)(qrow + 16 * ks + 8 * hi2);
            f32x4v x1 = *(const f32x4v*)(qrow + 16 * ks + 8 * hi2 + 4);
            FragU f;
            f.u[0] = cvtpk(x0.x * qsc, x0.y * qsc);
            f.u[1] = cvtpk(x0.z * qsc, x0.w * qsc);
            f.u[2] = cvtpk(x1.x * qsc, x1.y * qsc);
            f.u[3] = cvtpk(x1.z * qsc, x1.w * qsc);
            qf[ks] = f.v;
        }
    }

    f32x16 oacc[4];
    #pragma unroll
    for (int i = 0; i < 4; ++i)
        #pragma unroll
        for (int j = 0; j < 16; ++j) oacc[i][j] = 0.0f;
    float psum = 0.0f;

    const char* ktb = kimg + (size_t)b * NKB * TILEB;
    const char* vtb = vimg + (size_t)b * NKB * TILEB;
    const uint32_t* mrow = mbits + ((size_t)b * SLQ + (size_t)(q0 + 32 * wv + l31)) * 64;

    // 8 waves x (2 K-slices + 2 V-slices) x 1KB = one 16+16KB tile
    #define ISSUE(T, KB_, VB_)                                                \
        do {                                                                  \
            const char* ksrc_ = ktb + (size_t)(T) * TILEB;                    \
            const char* vsrc_ = vtb + (size_t)(T) * TILEB;                    \
            _Pragma("unroll")                                                 \
            for (int j = 0; j < 2; ++j) {                                     \
                const int ci = wv * 2 + j;                                    \
                __builtin_amdgcn_global_load_lds(                             \
                    (const uint32_t*)(ksrc_ + ci * 1024 + lane * 16),         \
                    (uint32_t*)((char*)(KB_) + ci * 1024), 16, 0, 0);         \
                __builtin_amdgcn_global_load_lds(                             \
                    (const uint32_t*)(vsrc_ + ci * 1024 + lane * 16),         \
                    (uint32_t*)((char*)(VB_) + ci * 1024), 16, 0, 0);         \
            }                                                                 \
        } while (0)

    // swapped QK^T of one 64-key tile from K buffer KL -> SACC[2]
    #define QKT(KL, SACC)                                                     \
        do {                                                                  \
            _Pragma("unroll")                                                 \
            for (int t = 0; t < 2; ++t) {                                     \
                const int row = 32 * t + l31;                                 \
                const char* krow = (const char*)(KL) + row * 256;             \
                const int sw = (row & 7) << 4;                                \
                f32x16 acc_;                                                  \
                _Pragma("unroll")                                             \
                for (int j = 0; j < 16; ++j) acc_[j] = 0.0f;                  \
                _Pragma("unroll")                                             \
                for (int ks = 0; ks < 8; ++ks) {                              \
                    bf16x8 af = *(const bf16x8*)(krow + ((32 * ks + 16 * hi2) ^ sw)); \
                    acc_ = __builtin_amdgcn_mfma_f32_32x32x16_bf16(af, qf[ks], acc_, 0, 0, 0); \
                }                                                             \
                SACC[t] = acc_;                                               \
            }                                                                 \
        } while (0)

    // SM(t) + PV(t): exp2+mask+pack from SACC/MQ, then P*V from V buffer VL
    #define SMPV(SACC, MQ, VL)                                                \
        do {                                                                  \
            _Pragma("unroll")                                                 \
            for (int t = 0; t < 2; ++t) {                                     \
                uint32_t pw[8];                                               \
                _Pragma("unroll")                                             \
                for (int rr = 0; rr < 4; ++rr) {                              \
                    const uint32_t mn = ((t ? (MQ).y : (MQ).x) >> (8 * rr + 4 * hi2)) & 0xFu; \
                    float em[4];                                              \
                    _Pragma("unroll")                                         \
                    for (int c = 0; c < 4; ++c) {                             \
                        const float e = EXP2(SACC[t][4 * rr + c]);            \
                        em[c] = ((mn >> c) & 1u) ? 0.0f : e;                  \
                    }                                                         \
                    psum += (em[0] + em[1]) + (em[2] + em[3]);                \
                    pw[2 * rr]     = cvtpk(em[0], em[1]);                     \
                    pw[2 * rr + 1] = cvtpk(em[2], em[3]);                     \
                }                                                             \
                _Pragma("unroll")                                             \
                for (int kss = 0; kss < 2; ++kss) {                           \
                    uint32_t a0 = pw[4 * kss + 0], b0 = pw[4 * kss + 2];      \
                    uint32_t a1 = pw[4 * kss + 1], b1 = pw[4 * kss + 3];      \
                    perm32swap(a0, b0);                                       \
                    perm32swap(a1, b1);                                       \
                    FragU af;                                                 \
                    af.u[0] = a0; af.u[1] = a1; af.u[2] = b0; af.u[3] = b1;   \
                    const int keyb = 64 * t + 32 * kss + 16 * hi2;            \
                    _Pragma("unroll")                                         \
                    for (int dt = 0; dt < 4; ++dt) {                          \
                        const int drow = 32 * dt + l31;                       \
                        const char* vrow = (const char*)(VL) + drow * 128;    \
                        const int sw8 = (drow & 15) << 3;                     \
                        FragU vf;                                             \
                        *(u32x2*)&vf.u[0] = *(const u32x2*)(vrow + ((keyb)     ^ sw8)); \
                        *(u32x2*)&vf.u[2] = *(const u32x2*)(vrow + ((keyb + 8) ^ sw8)); \
                        oacc[dt] = __builtin_amdgcn_mfma_f32_32x32x16_bf16(af.v, vf.v, oacc[dt], 0, 0, 0); \
                    }                                                         \
                }                                                             \
            }                                                                 \
        } while (0)

    // Full pipelined body for t in [0, 28]:
    // region { QKT(t+1) || SM(t)+PV(t) } ; zone { lgkm-bar; ISSUE(t+3);
    // load mq(t+2); vmcnt(6) -> tile t+2 resident; s_barrier }
    #define BODY_FULL(T_, SC, SP, MQV)                                        \
        do {                                                                  \
            const int t_ = (T_);                                              \
            short* klN = &k_lds[0][0]  + ((t_ + 1) % 3) * TILES;              \
            short* vlC = &vt_lds[0][0] + (t_ % 3) * TILES;                    \
            QKT(klN, SP);                                                     \
            SMPV(SC, MQV, vlC);                                               \
            barrier_lgkm();                                                   \
            ISSUE(t_ + 3, &k_lds[0][0] + (t_ % 3) * TILES,                    \
                          &vt_lds[0][0] + (t_ % 3) * TILES);                  \
            MQV = *(const u32x2*)(mrow + (t_ + 2) * 2);                       \
            asm volatile("s_waitcnt vmcnt(6)" ::: "memory");                  \
            __builtin_amdgcn_sched_barrier(0);                                \
            __builtin_amdgcn_s_barrier();                                     \
            __builtin_amdgcn_sched_barrier(0);                                \
        } while (0)

    f32x16 saccA[2], saccB[2];
    u32x2  mqA, mqB;

    // ---- prologue: 3 tiles in flight; tiles 0,1 resident; scores(0) ----
    ISSUE(0, &k_lds[0][0], &vt_lds[0][0]);
    ISSUE(1, &k_lds[0][0] + TILES, &vt_lds[0][0] + TILES);
    ISSUE(2, &k_lds[0][0] + 2 * TILES, &vt_lds[0][0] + 2 * TILES);
    mqA = *(const u32x2*)(mrow);
    mqB = *(const u32x2*)(mrow + 2);
    asm volatile("s_waitcnt vmcnt(6)" ::: "memory");   // 14 outstanding -> tiles 0,1 done
    __builtin_amdgcn_sched_barrier(0);
    __builtin_amdgcn_s_barrier();
    __builtin_amdgcn_sched_barrier(0);
    QKT(&k_lds[0][0], saccA);

    // ---- steady state: t = 0..27 (even: consume A produce B; odd: B->A) ----
    for (int t = 0; t < 28; t += 2) {
        BODY_FULL(t,     saccA, saccB, mqA);
        BODY_FULL(t + 1, saccB, saccA, mqB);
    }
    BODY_FULL(28, saccA, saccB, mqA);   // ISSUE(31) still valid

    // ---- tail t = 29, 30, 31 ----
    {   // t=29: QKT(30,buf0); consume saccB/mqB; PV buf2; drain all DMA
        QKT(&k_lds[0][0], saccA);
        SMPV(saccB, mqB, &vt_lds[0][0] + 2 * TILES);
        barrier_lgkm();
        mqB = *(const u32x2*)(mrow + 31 * 2);
        asm volatile("s_waitcnt vmcnt(0)" ::: "memory");
        __builtin_amdgcn_sched_barrier(0);
        __builtin_amdgcn_s_barrier();
        __builtin_amdgcn_sched_barrier(0);
    }
    {   // t=30: QKT(31,buf1); consume saccA/mqA; PV buf0 (no zone needed)
        QKT(&k_lds[0][0] + TILES, saccB);
        SMPV(saccA, mqA, &vt_lds[0][0]);
    }
    {   // t=31: consume saccB/mqB; PV buf1
        SMPV(saccB, mqB, &vt_lds[0][0] + TILES);
    }

    // ---- epilogue: combine halves of row-sums, normalize, store fp32 ----
    psum += __shfl_xor(psum, 32);
    float* obase = op + ((size_t)b * SLQ + (size_t)(q0 + 32 * wv)) * DD + l31;
    #pragma unroll
    for (int r = 0; r < 16; ++r) {
        const int qrow = (r & 3) + 8 * (r >> 2) + 4 * hi2;
        const float s  = __shfl(psum, qrow);
        const float rs = 1.0f / s;
        #pragma unroll
        for (int dt = 0; dt < 4; ++dt) {
            obase[(size_t)qrow * DD + 32 * dt] = oacc[dt][r] * rs;
        }
    }
}

extern "C" void kernel_launch(void* const* d_in, const int* in_sizes, int n_in,
                              void* d_out, int out_size, void* d_ws, size_t ws_size,
                              hipStream_t stream)
{
    const float* q = (const float*)d_in[0];
    const float* k = (const float*)d_in[1];
    const float* v = (const float*)d_in[2];
    const void*  m = d_in[3];
    float*       o = (float*)d_out;

    char*     kimg  = (char*)d_ws;                        // 16.78 MB
    char*     vimg  = kimg + (size_t)NB * NKB * TILEB;    // 16.78 MB
    uint32_t* mbits = (uint32_t*)(vimg + (size_t)NB * NKB * TILEB);  // 16.78 MB

    hipLaunchKernelGGL(prep_k, dim3(8192),  dim3(256), 0, stream, k, kimg);
    hipLaunchKernelGGL(prep_v, dim3(8192),  dim3(256), 0, stream, v, vimg);
    hipLaunchKernelGGL(prep_m, dim3(16384), dim3(256), 0, stream, m, mbits);
    hipLaunchKernelGGL(attn_main, dim3((NB * SLQ) / QTILE), dim3(512), 0, stream,
                       q, kimg, vimg, mbits, o);
}

// Round 16
// 238.758 us; speedup vs baseline: 1.0797x; 1.0797x over previous
//
#include <hip/hip_runtime.h>
#include <stdint.h>

// Problem constants (B, LQ, LK, D fixed by the reference)
#define NB    32
#define SLQ   2048
#define SLK   2048
#define DD    128
#define QTILE 128          // q rows per workgroup (4 waves x 32)
#define KVB   64           // keys per block iteration
#define NKB   (SLK / KVB)  // 32

typedef __attribute__((ext_vector_type(8)))  short    bf16x8;
typedef __attribute__((ext_vector_type(16))) float    f32x16;
typedef __attribute__((ext_vector_type(4)))  float    f32x4v;
typedef __attribute__((ext_vector_type(4)))  uint32_t u32x4;
typedef __attribute__((ext_vector_type(2)))  uint32_t u32x2;

union FragU { uint32_t u[4]; bf16x8 v; };

// HW packed f32->bf16 (RNE), 1 inst per pair
__device__ __forceinline__ uint32_t cvtpk(float lo, float hi) {
    uint32_t r;
    asm("v_cvt_pk_bf16_f32 %0, %1, %2" : "=v"(r) : "v"(lo), "v"(hi));
    return r;
}
// a' = {lanes<32: a, lanes>=32: b[lane-32]}; b' = {lanes<32: a[lane+32], lanes>=32: b}
__device__ __forceinline__ void perm32swap(uint32_t& a, uint32_t& b) {
    asm("v_permlane32_swap_b32 %0, %1" : "+v"(a), "+v"(b));
}
// 16 mask bytes (0/1) -> 16 bits
__device__ __forceinline__ uint32_t pack16(u32x4 a) {
    uint32_t r0 = (((a.x & 0x01010101u) * 0x01020408u) >> 24) & 0xFu;
    uint32_t r1 = (((a.y & 0x01010101u) * 0x01020408u) >> 24) & 0xFu;
    uint32_t r2 = (((a.z & 0x01010101u) * 0x01020408u) >> 24) & 0xFu;
    uint32_t r3 = (((a.w & 0x01010101u) * 0x01020408u) >> 24) & 0xFu;
    return r0 | (r1 << 4) | (r2 << 8) | (r3 << 12);
}
#if __has_builtin(__builtin_amdgcn_exp2f)
#define EXP2(x) __builtin_amdgcn_exp2f(x)
#else
#define EXP2(x) exp2f(x)
#endif

// ---------------------------------------------------------------------------
// prep_m (R14-validated, verbatim): bool mask -> 1 bit/key, [b][q][64 words].
// Removes the 134MB 64B-granule byte stream + pack VALU from the hot loop.
// ---------------------------------------------------------------------------
__global__ __launch_bounds__(256, 8)
void prep_m(const void* __restrict__ mp, uint32_t* __restrict__ mbits)
{
    __shared__ int det_flags;
    if (threadIdx.x == 0) det_flags = 0;
    __syncthreads();
    {
        const u32x4 w = *(const u32x4*)((const char*)mp + threadIdx.x * 16);
        const uint32_t any_hi    = (w.x | w.y | w.z | w.w) & 0xFFFFFF00u;
        const uint32_t any_mod84 = (w.y | w.w) & 0xFFu;
        const int f = (any_hi ? 1 : 0) | (any_mod84 ? 2 : 0);
        if (f) atomicOr(&det_flags, f);
    }
    __syncthreads();
    const int mflags = det_flags;
    const int mmode  = (mflags & 1) ? 0 : ((mflags & 2) ? 1 : 2);  // 0=u8,1=i32,2=i64

    const int t   = blockIdx.x * 256 + threadIdx.x;  // 4,194,304 total
    const int k32 = t & 63;          // 32-key group
    const int q   = (t >> 6) & 2047;
    const int b   = t >> 17;
    const size_t e0 = ((size_t)b * SLQ + q) * SLK + (size_t)k32 * 32;
    uint32_t bits;
    if (mmode == 0) {
        const uint8_t* src = (const uint8_t*)mp + e0;
        u32x4 a = *(const u32x4*)(src);
        u32x4 c = *(const u32x4*)(src + 16);
        bits = pack16(a) | (pack16(c) << 16);
    } else if (mmode == 1) {
        const uint32_t* s = (const uint32_t*)mp + e0;
        bits = 0;
        for (int j = 0; j < 32; ++j) bits |= (s[j] ? 1u : 0u) << j;
    } else {
        const uint64_t* s = (const uint64_t*)mp + e0;
        bits = 0;
        for (int j = 0; j < 32; ++j) bits |= (s[j] ? 1u : 0u) << j;
    }
    mbits[((size_t)b * SLQ + q) * 64 + k32] = bits;
}

// ---------------------------------------------------------------------------
// Main kernel: R5 (205us champion) with (1) mask via prepacked bits read
// directly from global (no m_lds, no pack16, no mask staging), (2) no setprio.
// Everything else byte-identical to R5.
// ---------------------------------------------------------------------------
__global__ __launch_bounds__(256, 2)
void attn_fwd(const float* __restrict__ qp, const float* __restrict__ kp,
              const float* __restrict__ vp, const uint32_t* __restrict__ mbits,
              float* __restrict__ op)
{
    // Single-buffer LDS (R5-proven schedule): 16KB K + 16KB V^T
    __shared__ short k_lds[KVB * DD];    // [64 key][128 d] bf16, 16B-XOR swizzle
    __shared__ short vt_lds[DD * KVB];   // [128 d][64 key] bf16, 8B-XOR swizzle

    const int tid  = threadIdx.x;
    const int lane = tid & 63;
    const int wv   = tid >> 6;   // wave 0..3
    const int l31  = lane & 31;
    const int hi2  = lane >> 5;  // 0/1

    // XCD-chunked swizzle: 512 WGs, 8 XCDs -> each XCD gets 64 consecutive ids
    const int bid = blockIdx.x;
    const int wg  = (bid & 7) * 64 + (bid >> 3);
    const int b   = wg >> 4;            // batch
    const int q0  = (wg & 15) * QTILE;  // q tile origin

    // scale = log2(e)/sqrt(128): scores land in log2 units -> softmax is bare v_exp
    const float qsc = 0.12751744846458246f;

    // ---- persistent Q fragments (B-operand of swapped QK^T) ----
    bf16x8 qf[8];
    {
        const float* qrow = qp + ((size_t)b * SLQ + (size_t)(q0 + wv * 32 + l31)) * DD;
        #pragma unroll
        for (int ks = 0; ks < 8; ++ks) {
            f32x4v x0 = *(const f32x4v*)(qrow + 16 * ks + 8 * hi2);
            f32x4v x1 = *(const f32x4v*)(qrow + 16 * ks + 8 * hi2 + 4);
            FragU f;
            f.u[0] = cvtpk(x0.x * qsc, x0.y * qsc);
            f.u[1] = cvtpk(x0.z * qsc, x0.w * qsc);
            f.u[2] = cvtpk(x1.x * qsc, x1.y * qsc);
            f.u[3] = cvtpk(x1.z * qsc, x1.w * qsc);
            qf[ks] = f.v;
        }
    }

    f32x16 oacc[4];
    #pragma unroll
    for (int i = 0; i < 4; ++i)
        #pragma unroll
        for (int j = 0; j < 16; ++j) oacc[i][j] = 0.0f;
    float psum = 0.0f;

    const float* kb0 = kp + (size_t)b * SLK * DD;
    const float* vb0 = vp + (size_t)b * SLK * DD;
    // this lane's q-row bit-mask stream (8B per tile, L2-resident)
    const uint32_t* mrow = mbits + ((size_t)b * SLQ + (size_t)(q0 + 32 * wv + l31)) * 64;

    // ---- prefetch registers (T14: issue-early / write-late) ----
    f32x4v kreg[8];
    float  vreg[32];

    const int vd  = tid & 127;       // d-row this thread stages for V^T
    const int vkh = tid >> 7;        // key half (0: keys 0-31, 1: keys 32-63)
    const int swv = (vd & 15) << 3;  // V^T 8B-granular XOR

    #define LOAD_TILE(KB)                                                         \
        do {                                                                      \
            const int k0_ = (KB) * KVB;                                           \
            const float* kbase_ = kb0 + (size_t)k0_ * DD;                         \
            _Pragma("unroll")                                                     \
            for (int j = 0; j < 8; ++j)                                           \
                kreg[j] = *(const f32x4v*)(kbase_ + (j * 256 + tid) * 4);         \
            const float* vcol_ = vb0 + ((size_t)k0_ + 32 * vkh) * DD + vd;        \
            _Pragma("unroll")                                                     \
            for (int jj = 0; jj < 32; ++jj) vreg[jj] = vcol_[(size_t)jj * DD];    \
        } while (0)

    #define WRITE_LDS(KB)                                                         \
        do {                                                                      \
            _Pragma("unroll")                                                     \
            for (int j = 0; j < 8; ++j) {                                         \
                const int flat = (j * 256 + tid) * 4;                             \
                const int kk   = flat >> 7;                                       \
                const int dd2  = (flat & 127) * 2;                                \
                u32x2 w2;                                                         \
                w2.x = cvtpk(kreg[j].x, kreg[j].y);                               \
                w2.y = cvtpk(kreg[j].z, kreg[j].w);                               \
                *(u32x2*)((char*)k_lds + kk * 256 + (dd2 ^ ((kk & 7) << 4))) = w2;\
            }                                                                     \
            {                                                                     \
                char* vrow_ = (char*)vt_lds + vd * 128;                           \
                _Pragma("unroll")                                                 \
                for (int j = 0; j < 8; ++j) {                                     \
                    u32x2 w2;                                                     \
                    w2.x = cvtpk(vreg[4 * j + 0], vreg[4 * j + 1]);               \
                    w2.y = cvtpk(vreg[4 * j + 2], vreg[4 * j + 3]);               \
                    *(u32x2*)(vrow_ + ((vkh * 64 + 8 * j) ^ swv)) = w2;           \
                }                                                                 \
            }                                                                     \
        } while (0)

    LOAD_TILE(0);

    for (int kb = 0; kb < NKB; ++kb) {
        // ---- write LDS from prefetch regs; vmcnt wait lands HERE, pinned by
        //      the barrier structure (a full compute phase has hidden the loads)
        WRITE_LDS(kb);
        __syncthreads();

        // ---- issue next tile's loads + this tile's mask bits, pinned above
        //      compute; QK^T hides the mask-load latency ----
        if (kb + 1 < NKB) LOAD_TILE(kb + 1);
        const u32x2 mq = *(const u32x2*)(mrow + kb * 2);
        __builtin_amdgcn_sched_barrier(0);

        // ---- swapped QK^T: sacc[t] = S^T (keys 32t.. x 32 q), log2 units ----
        f32x16 sacc[2];
        #pragma unroll
        for (int t = 0; t < 2; ++t)
            #pragma unroll
            for (int j = 0; j < 16; ++j) sacc[t][j] = 0.0f;
        #pragma unroll
        for (int t = 0; t < 2; ++t) {
            const int row = 32 * t + l31;
            const char* krow = (const char*)k_lds + row * 256;
            const int sw = (row & 7) << 4;
            #pragma unroll
            for (int ks = 0; ks < 8; ++ks) {
                bf16x8 af = *(const bf16x8*)(krow + ((32 * ks + 16 * hi2) ^ sw));
                sacc[t] = __builtin_amdgcn_mfma_f32_32x32x16_bf16(af, qf[ks], sacc[t], 0, 0, 0);
            }
        }

        // ---- softmax: p = exp2(s'), mask via bits, f32 row-sum, pack bf16 ----
        uint32_t pw[2][8];
        #pragma unroll
        for (int t = 0; t < 2; ++t) {
            #pragma unroll
            for (int rr = 0; rr < 4; ++rr) {
                const uint32_t mn = ((t ? mq.y : mq.x) >> (8 * rr + 4 * hi2)) & 0xFu;
                float em[4];
                #pragma unroll
                for (int c = 0; c < 4; ++c) {
                    const float e = EXP2(sacc[t][4 * rr + c]);
                    em[c] = ((mn >> c) & 1u) ? 0.0f : e;
                }
                psum += (em[0] + em[1]) + (em[2] + em[3]);
                pw[t][2 * rr]     = cvtpk(em[0], em[1]);
                pw[t][2 * rr + 1] = cvtpk(em[2], em[3]);
            }
        }

        // ---- PV: O[32q x 128d] += P[32x64] * V[64x128] ----
        #pragma unroll
        for (int t = 0; t < 2; ++t) {
            #pragma unroll
            for (int kss = 0; kss < 2; ++kss) {
                uint32_t a0 = pw[t][4 * kss + 0], b0 = pw[t][4 * kss + 2];
                uint32_t a1 = pw[t][4 * kss + 1], b1 = pw[t][4 * kss + 3];
                perm32swap(a0, b0);
                perm32swap(a1, b1);
                FragU af;
                af.u[0] = a0; af.u[1] = a1; af.u[2] = b0; af.u[3] = b1;
                const int keyb = 64 * t + 32 * kss + 16 * hi2;
                #pragma unroll
                for (int dt = 0; dt < 4; ++dt) {
                    const int drow = 32 * dt + l31;
                    const char* vrow = (const char*)vt_lds + drow * 128;
                    const int sw8 = (drow & 15) << 3;
                    FragU vf;
                    *(u32x2*)&vf.u[0] = *(const u32x2*)(vrow + ((keyb)     ^ sw8));
                    *(u32x2*)&vf.u[2] = *(const u32x2*)(vrow + ((keyb + 8) ^ sw8));
                    oacc[dt] = __builtin_amdgcn_mfma_f32_32x32x16_bf16(af.v, vf.v, oacc[dt], 0, 0, 0);
                }
            }
        }
        __syncthreads();
    }

    // ---- epilogue: combine halves of row-sums, normalize, store fp32 ----
    psum += __shfl_xor(psum, 32);
    float* obase = op + ((size_t)b * SLQ + (size_t)(q0 + 32 * wv)) * DD + l31;
    #pragma unroll
    for (int r = 0; r < 16; ++r) {
        const int qrow = (r & 3) + 8 * (r >> 2) + 4 * hi2;
        const float s  = __shfl(psum, qrow);
        const float rs = 1.0f / s;
        #pragma unroll
        for (int dt = 0; dt < 4; ++dt) {
            obase[(size_t)qrow * DD + 32 * dt] = oacc[dt][r] * rs;
        }
    }
}

extern "C" void kernel_launch(void* const* d_in, const int* in_sizes, int n_in,
                              void* d_out, int out_size, void* d_ws, size_t ws_size,
                              hipStream_t stream)
{
    const float* q = (const float*)d_in[0];
    const float* k = (const float*)d_in[1];
    const float* v = (const float*)d_in[2];
    const void*  m = d_in[3];
    float*       o = (float*)d_out;
    uint32_t*    mbits = (uint32_t*)d_ws;   // 16.78 MB

    hipLaunchKernelGGL(prep_m, dim3(16384), dim3(256), 0, stream, m, mbits);
    hipLaunchKernelGGL(attn_fwd, dim3((NB * SLQ) / QTILE), dim3(256), 0, stream,
                       q, k, v, mbits, o);
}

// Round 17
// 206.148 us; speedup vs baseline: 1.2505x; 1.1582x over previous
//
#include <hip/hip_runtime.h>
#include <stdint.h>

// ============================================================================
// FINAL (session champion, R5 verbatim): 205.2 us measured.
// B=32, LQ=LK=2048, D=128 masked attention, fp32 in/out, unstable-exp softmax
// (faithful to reference: no max-subtraction), bf16 MFMA compute.
//
// Structure: 512 blocks x 256 thr (4 waves); QTILE=128 (32 q-rows/wave);
// KV blocks of 64 keys; single-buffer LDS with the proven 2-barrier schedule:
//   WRITE_LDS (vmcnt waits land here, covered by previous compute phase)
//   -> barrier -> LOAD_TILE(next) pinned above compute via sched_barrier
//   -> swapped QK^T (mfma(K,Q), scores in log2 units: scale=log2(e)/sqrt(D))
//   -> exp2+mask-bit softmax, f32 row-sums, v_cvt_pk_bf16_f32 pack
//   -> PV via permlane32_swap-built A-frags + 8B-XOR-swizzled V^T reads
//   -> barrier.
// Known residual: latency plateau at ~205us (5x above HBM roofline); six
// structural variants (DMA staging, 3-deep pipeline, 16x16 low-reg, split
// phases, mask prepack, no-drain barriers) all measure 205-215us. Breaking
// it requires a fully co-designed schedule (HK/AITER-class), not grafts.
// ============================================================================

#define NB    32
#define SLQ   2048
#define SLK   2048
#define DD    128
#define QTILE 128          // q rows per workgroup (4 waves x 32)
#define KVB   64           // keys per block iteration
#define NKB   (SLK / KVB)  // 32

typedef __attribute__((ext_vector_type(8)))  short    bf16x8;
typedef __attribute__((ext_vector_type(16))) float    f32x16;
typedef __attribute__((ext_vector_type(4)))  float    f32x4v;
typedef __attribute__((ext_vector_type(4)))  uint32_t u32x4;
typedef __attribute__((ext_vector_type(2)))  uint32_t u32x2;

union FragU { uint32_t u[4]; bf16x8 v; };

// HW packed f32->bf16 (RNE), 1 inst per pair
__device__ __forceinline__ uint32_t cvtpk(float lo, float hi) {
    uint32_t r;
    asm("v_cvt_pk_bf16_f32 %0, %1, %2" : "=v"(r) : "v"(lo), "v"(hi));
    return r;
}
// a' = {lanes<32: a, lanes>=32: b[lane-32]}; b' = {lanes<32: a[lane+32], lanes>=32: b}
__device__ __forceinline__ void perm32swap(uint32_t& a, uint32_t& b) {
    asm("v_permlane32_swap_b32 %0, %1" : "+v"(a), "+v"(b));
}
// 16 mask bytes (0/1) -> 16 bits
__device__ __forceinline__ uint32_t pack16(u32x4 a) {
    uint32_t r0 = (((a.x & 0x01010101u) * 0x01020408u) >> 24) & 0xFu;
    uint32_t r1 = (((a.y & 0x01010101u) * 0x01020408u) >> 24) & 0xFu;
    uint32_t r2 = (((a.z & 0x01010101u) * 0x01020408u) >> 24) & 0xFu;
    uint32_t r3 = (((a.w & 0x01010101u) * 0x01020408u) >> 24) & 0xFu;
    return r0 | (r1 << 4) | (r2 << 8) | (r3 << 12);
}
#if __has_builtin(__builtin_amdgcn_exp2f)
#define EXP2(x) __builtin_amdgcn_exp2f(x)
#else
#define EXP2(x) exp2f(x)
#endif

__global__ __launch_bounds__(256, 2)
void attn_fwd(const float* __restrict__ qp, const float* __restrict__ kp,
              const float* __restrict__ vp, const void* __restrict__ mp,
              float* __restrict__ op)
{
    // Single-buffer LDS: 16KB K + 16KB V^T + 1KB mask bits
    __shared__ short    k_lds[KVB * DD];    // [64 key][128 d] bf16, 16B-XOR swizzle
    __shared__ short    vt_lds[DD * KVB];   // [128 d][64 key] bf16, 8B-XOR swizzle
    __shared__ uint32_t m_lds[QTILE * 2];   // [128 q][2] dwords of key-bits
    __shared__ int      det_flags;

    const int tid  = threadIdx.x;
    const int lane = tid & 63;
    const int wv   = tid >> 6;   // wave 0..3
    const int l31  = lane & 31;
    const int hi2  = lane >> 5;  // 0/1

    // XCD-chunked swizzle: 512 WGs, 8 XCDs -> each XCD gets 64 consecutive ids
    const int bid = blockIdx.x;
    const int wg  = (bid & 7) * 64 + (bid >> 3);
    const int b   = wg >> 4;            // batch
    const int q0  = (wg & 15) * QTILE;  // q tile origin

    // ---- mask dtype self-detection (R2 FETCH proved u8; keep as safety) ----
    if (tid == 0) det_flags = 0;
    __syncthreads();
    {
        const u32x4 w = *(const u32x4*)((const char*)mp + tid * 16);
        const uint32_t any_hi    = (w.x | w.y | w.z | w.w) & 0xFFFFFF00u;
        const uint32_t any_mod84 = (w.y | w.w) & 0xFFu;
        const int f = (any_hi ? 1 : 0) | (any_mod84 ? 2 : 0);
        if (f) atomicOr(&det_flags, f);
    }
    __syncthreads();
    const int mflags = det_flags;
    const int mmode  = (mflags & 1) ? 0 : ((mflags & 2) ? 1 : 2);  // 0=u8, 1=i32, 2=i64

    // scale = log2(e)/sqrt(128): scores land in log2 units -> softmax is bare v_exp
    const float qsc = 0.12751744846458246f;

    // ---- persistent Q fragments (B-operand of swapped QK^T) ----
    bf16x8 qf[8];
    {
        const float* qrow = qp + ((size_t)b * SLQ + (size_t)(q0 + wv * 32 + l31)) * DD;
        #pragma unroll
        for (int ks = 0; ks < 8; ++ks) {
            f32x4v x0 = *(const f32x4v*)(qrow + 16 * ks + 8 * hi2);
            f32x4v x1 = *(const f32x4v*)(qrow + 16 * ks + 8 * hi2 + 4);
            FragU f;
            f.u[0] = cvtpk(x0.x * qsc, x0.y * qsc);
            f.u[1] = cvtpk(x0.z * qsc, x0.w * qsc);
            f.u[2] = cvtpk(x1.x * qsc, x1.y * qsc);
            f.u[3] = cvtpk(x1.z * qsc, x1.w * qsc);
            qf[ks] = f.v;
        }
    }

    f32x16 oacc[4];
    #pragma unroll
    for (int i = 0; i < 4; ++i)
        #pragma unroll
        for (int j = 0; j < 16; ++j) oacc[i][j] = 0.0f;
    float psum = 0.0f;

    const float* kb0 = kp + (size_t)b * SLK * DD;
    const float* vb0 = vp + (size_t)b * SLK * DD;
    const size_t mrow0 = ((size_t)b * SLQ + q0) * SLK;

    // ---- prefetch registers (T14: issue-early / write-late) ----
    f32x4v kreg[8];
    float  vreg[32];
    u32x4  mreg[2];

    const int vd  = tid & 127;       // d-row this thread stages for V^T
    const int vkh = tid >> 7;        // key half (0: keys 0-31, 1: keys 32-63)
    const int mqq = tid >> 1;        // mask q row
    const int mh  = tid & 1;         // mask key half
    const int swv = (vd & 15) << 3;  // V^T 8B-granular XOR

    #define LOAD_TILE(KB)                                                         \
        do {                                                                      \
            const int k0_ = (KB) * KVB;                                           \
            const float* kbase_ = kb0 + (size_t)k0_ * DD;                         \
            _Pragma("unroll")                                                     \
            for (int j = 0; j < 8; ++j)                                           \
                kreg[j] = *(const f32x4v*)(kbase_ + (j * 256 + tid) * 4);         \
            const float* vcol_ = vb0 + ((size_t)k0_ + 32 * vkh) * DD + vd;        \
            _Pragma("unroll")                                                     \
            for (int jj = 0; jj < 32; ++jj) vreg[jj] = vcol_[(size_t)jj * DD];    \
            if (mmode == 0) {                                                     \
                const uint8_t* ms_ = (const uint8_t*)mp + mrow0 +                 \
                                     (size_t)mqq * SLK + k0_ + mh * 32;           \
                mreg[0] = *(const u32x4*)(ms_);                                   \
                mreg[1] = *(const u32x4*)(ms_ + 16);                              \
            }                                                                     \
        } while (0)

    #define WRITE_LDS(KB)                                                         \
        do {                                                                      \
            _Pragma("unroll")                                                     \
            for (int j = 0; j < 8; ++j) {                                         \
                const int flat = (j * 256 + tid) * 4;                             \
                const int kk   = flat >> 7;                                       \
                const int dd2  = (flat & 127) * 2;                                \
                u32x2 w2;                                                         \
                w2.x = cvtpk(kreg[j].x, kreg[j].y);                               \
                w2.y = cvtpk(kreg[j].z, kreg[j].w);                               \
                *(u32x2*)((char*)k_lds + kk * 256 + (dd2 ^ ((kk & 7) << 4))) = w2;\
            }                                                                     \
            {                                                                     \
                char* vrow_ = (char*)vt_lds + vd * 128;                           \
                _Pragma("unroll")                                                 \
                for (int j = 0; j < 8; ++j) {                                     \
                    u32x2 w2;                                                     \
                    w2.x = cvtpk(vreg[4 * j + 0], vreg[4 * j + 1]);               \
                    w2.y = cvtpk(vreg[4 * j + 2], vreg[4 * j + 3]);               \
                    *(u32x2*)(vrow_ + ((vkh * 64 + 8 * j) ^ swv)) = w2;           \
                }                                                                 \
            }                                                                     \
            if (mmode == 0) {                                                     \
                m_lds[mqq * 2 + mh] = pack16(mreg[0]) | (pack16(mreg[1]) << 16);  \
            } else {                                                              \
                const size_t e0_ = mrow0 + (size_t)mqq * SLK + (KB) * KVB + mh * 32; \
                uint32_t bits = 0;                                                \
                if (mmode == 1) {                                                 \
                    const uint32_t* s_ = (const uint32_t*)mp + e0_;               \
                    for (int j = 0; j < 32; ++j) bits |= (s_[j] ? 1u : 0u) << j;  \
                } else {                                                          \
                    const uint64_t* s_ = (const uint64_t*)mp + e0_;               \
                    for (int j = 0; j < 32; ++j) bits |= (s_[j] ? 1u : 0u) << j;  \
                }                                                                 \
                m_lds[mqq * 2 + mh] = bits;                                       \
            }                                                                     \
        } while (0)

    LOAD_TILE(0);

    for (int kb = 0; kb < NKB; ++kb) {
        // ---- write LDS from prefetch regs; vmcnt wait lands HERE, pinned by
        //      the barrier structure (a full compute phase has hidden the loads)
        WRITE_LDS(kb);
        __syncthreads();

        // ---- issue next tile's loads, pinned above compute ----
        if (kb + 1 < NKB) LOAD_TILE(kb + 1);
        __builtin_amdgcn_sched_barrier(0);

        // ---- swapped QK^T: sacc[t] = S^T (keys 32t.. x 32 q), log2 units ----
        f32x16 sacc[2];
        #pragma unroll
        for (int t = 0; t < 2; ++t)
            #pragma unroll
            for (int j = 0; j < 16; ++j) sacc[t][j] = 0.0f;
        __builtin_amdgcn_s_setprio(1);
        #pragma unroll
        for (int t = 0; t < 2; ++t) {
            const int row = 32 * t + l31;
            const char* krow = (const char*)k_lds + row * 256;
            const int sw = (row & 7) << 4;
            #pragma unroll
            for (int ks = 0; ks < 8; ++ks) {
                bf16x8 af = *(const bf16x8*)(krow + ((32 * ks + 16 * hi2) ^ sw));
                sacc[t] = __builtin_amdgcn_mfma_f32_32x32x16_bf16(af, qf[ks], sacc[t], 0, 0, 0);
            }
        }
        __builtin_amdgcn_s_setprio(0);

        // ---- softmax: p = exp2(s'), mask via bit tile, f32 row-sum, pack bf16 ----
        const u32x2 mq = *(const u32x2*)(&m_lds[(32 * wv + l31) * 2]);
        uint32_t pw[2][8];
        #pragma unroll
        for (int t = 0; t < 2; ++t) {
            #pragma unroll
            for (int rr = 0; rr < 4; ++rr) {
                const uint32_t mn = ((t ? mq.y : mq.x) >> (8 * rr + 4 * hi2)) & 0xFu;
                float em[4];
                #pragma unroll
                for (int c = 0; c < 4; ++c) {
                    const float e = EXP2(sacc[t][4 * rr + c]);
                    em[c] = ((mn >> c) & 1u) ? 0.0f : e;
                }
                psum += (em[0] + em[1]) + (em[2] + em[3]);
                pw[t][2 * rr]     = cvtpk(em[0], em[1]);
                pw[t][2 * rr + 1] = cvtpk(em[2], em[3]);
            }
        }

        // ---- PV: O[32q x 128d] += P[32x64] * V[64x128] ----
        #pragma unroll
        for (int t = 0; t < 2; ++t) {
            #pragma unroll
            for (int kss = 0; kss < 2; ++kss) {
                uint32_t a0 = pw[t][4 * kss + 0], b0 = pw[t][4 * kss + 2];
                uint32_t a1 = pw[t][4 * kss + 1], b1 = pw[t][4 * kss + 3];
                perm32swap(a0, b0);
                perm32swap(a1, b1);
                FragU af;
                af.u[0] = a0; af.u[1] = a1; af.u[2] = b0; af.u[3] = b1;
                const int keyb = 64 * t + 32 * kss + 16 * hi2;
                __builtin_amdgcn_s_setprio(1);
                #pragma unroll
                for (int dt = 0; dt < 4; ++dt) {
                    const int drow = 32 * dt + l31;
                    const char* vrow = (const char*)vt_lds + drow * 128;
                    const int sw8 = (drow & 15) << 3;
                    FragU vf;
                    *(u32x2*)&vf.u[0] = *(const u32x2*)(vrow + ((keyb)     ^ sw8));
                    *(u32x2*)&vf.u[2] = *(const u32x2*)(vrow + ((keyb + 8) ^ sw8));
                    oacc[dt] = __builtin_amdgcn_mfma_f32_32x32x16_bf16(af.v, vf.v, oacc[dt], 0, 0, 0);
                }
                __builtin_amdgcn_s_setprio(0);
            }
        }
        __syncthreads();
    }

    // ---- epilogue: combine halves of row-sums, normalize, store fp32 ----
    psum += __shfl_xor(psum, 32);
    float* obase = op + ((size_t)b * SLQ + (size_t)(q0 + 32 * wv)) * DD + l31;
    #pragma unroll
    for (int r = 0; r < 16; ++r) {
        const int qrow = (r & 3) + 8 * (r >> 2) + 4 * hi2;
        const float s  = __shfl(psum, qrow);
        const float rs = 1.0f / s;
        #pragma unroll
        for (int dt = 0; dt < 4; ++dt) {
            obase[(size_t)qrow * DD + 32 * dt] = oacc[dt][r] * rs;
        }
    }
}

extern "C" void kernel_launch(void* const* d_in, const int* in_sizes, int n_in,
                              void* d_out, int out_size, void* d_ws, size_t ws_size,
                              hipStream_t stream)
{
    const float* q = (const float*)d_in[0];
    const float* k = (const float*)d_in[1];
    const float* v = (const float*)d_in[2];
    const void*  m = d_in[3];
    float*       o = (float*)d_out;
    hipLaunchKernelGGL(attn_fwd, dim3((NB * SLQ) / QTILE), dim3(256), 0, stream,
                       q, k, v, m, o);
}

// Round 18
// 205.289 us; speedup vs baseline: 1.2557x; 1.0042x over previous
//
#include <hip/hip_runtime.h>
#include <stdint.h>

// ============================================================================
// R18: champion (R5/R17, 205-206us) + ONE change: V^T LDS layout moves from
// 8B-granular XOR (PV = 2x ds_read_b64) to 16B-granular XOR (PV = 1x
// ds_read_b128). Targets the largest remaining LDS-instruction stream:
// per wave-iter PV reads 32 -> 16, V staging writes 8 -> 4.
// Everything else byte-identical to the champion for a clean A/B.
// ============================================================================

#define NB    32
#define SLQ   2048
#define SLK   2048
#define DD    128
#define QTILE 128          // q rows per workgroup (4 waves x 32)
#define KVB   64           // keys per block iteration
#define NKB   (SLK / KVB)  // 32

typedef __attribute__((ext_vector_type(8)))  short    bf16x8;
typedef __attribute__((ext_vector_type(16))) float    f32x16;
typedef __attribute__((ext_vector_type(4)))  float    f32x4v;
typedef __attribute__((ext_vector_type(4)))  uint32_t u32x4;
typedef __attribute__((ext_vector_type(2)))  uint32_t u32x2;

union FragU { uint32_t u[4]; bf16x8 v; };

// HW packed f32->bf16 (RNE), 1 inst per pair
__device__ __forceinline__ uint32_t cvtpk(float lo, float hi) {
    uint32_t r;
    asm("v_cvt_pk_bf16_f32 %0, %1, %2" : "=v"(r) : "v"(lo), "v"(hi));
    return r;
}
// a' = {lanes<32: a, lanes>=32: b[lane-32]}; b' = {lanes<32: a[lane+32], lanes>=32: b}
__device__ __forceinline__ void perm32swap(uint32_t& a, uint32_t& b) {
    asm("v_permlane32_swap_b32 %0, %1" : "+v"(a), "+v"(b));
}
// 16 mask bytes (0/1) -> 16 bits
__device__ __forceinline__ uint32_t pack16(u32x4 a) {
    uint32_t r0 = (((a.x & 0x01010101u) * 0x01020408u) >> 24) & 0xFu;
    uint32_t r1 = (((a.y & 0x01010101u) * 0x01020408u) >> 24) & 0xFu;
    uint32_t r2 = (((a.z & 0x01010101u) * 0x01020408u) >> 24) & 0xFu;
    uint32_t r3 = (((a.w & 0x01010101u) * 0x01020408u) >> 24) & 0xFu;
    return r0 | (r1 << 4) | (r2 << 8) | (r3 << 12);
}
#if __has_builtin(__builtin_amdgcn_exp2f)
#define EXP2(x) __builtin_amdgcn_exp2f(x)
#else
#define EXP2(x) exp2f(x)
#endif

__global__ __launch_bounds__(256, 2)
void attn_fwd(const float* __restrict__ qp, const float* __restrict__ kp,
              const float* __restrict__ vp, const void* __restrict__ mp,
              float* __restrict__ op)
{
    // Single-buffer LDS: 16KB K + 16KB V^T + 1KB mask bits
    __shared__ short    k_lds[KVB * DD];    // [64 key][128 d] bf16, 16B-XOR swizzle
    __shared__ short    vt_lds[DD * KVB];   // [128 d][64 key] bf16, 16B-XOR swizzle
    __shared__ uint32_t m_lds[QTILE * 2];   // [128 q][2] dwords of key-bits
    __shared__ int      det_flags;

    const int tid  = threadIdx.x;
    const int lane = tid & 63;
    const int wv   = tid >> 6;   // wave 0..3
    const int l31  = lane & 31;
    const int hi2  = lane >> 5;  // 0/1

    // XCD-chunked swizzle: 512 WGs, 8 XCDs -> each XCD gets 64 consecutive ids
    const int bid = blockIdx.x;
    const int wg  = (bid & 7) * 64 + (bid >> 3);
    const int b   = wg >> 4;            // batch
    const int q0  = (wg & 15) * QTILE;  // q tile origin

    // ---- mask dtype self-detection (R2 FETCH proved u8; keep as safety) ----
    if (tid == 0) det_flags = 0;
    __syncthreads();
    {
        const u32x4 w = *(const u32x4*)((const char*)mp + tid * 16);
        const uint32_t any_hi    = (w.x | w.y | w.z | w.w) & 0xFFFFFF00u;
        const uint32_t any_mod84 = (w.y | w.w) & 0xFFu;
        const int f = (any_hi ? 1 : 0) | (any_mod84 ? 2 : 0);
        if (f) atomicOr(&det_flags, f);
    }
    __syncthreads();
    const int mflags = det_flags;
    const int mmode  = (mflags & 1) ? 0 : ((mflags & 2) ? 1 : 2);  // 0=u8, 1=i32, 2=i64

    // scale = log2(e)/sqrt(128): scores land in log2 units -> softmax is bare v_exp
    const float qsc = 0.12751744846458246f;

    // ---- persistent Q fragments (B-operand of swapped QK^T) ----
    bf16x8 qf[8];
    {
        const float* qrow = qp + ((size_t)b * SLQ + (size_t)(q0 + wv * 32 + l31)) * DD;
        #pragma unroll
        for (int ks = 0; ks < 8; ++ks) {
            f32x4v x0 = *(const f32x4v*)(qrow + 16 * ks + 8 * hi2);
            f32x4v x1 = *(const f32x4v*)(qrow + 16 * ks + 8 * hi2 + 4);
            FragU f;
            f.u[0] = cvtpk(x0.x * qsc, x0.y * qsc);
            f.u[1] = cvtpk(x0.z * qsc, x0.w * qsc);
            f.u[2] = cvtpk(x1.x * qsc, x1.y * qsc);
            f.u[3] = cvtpk(x1.z * qsc, x1.w * qsc);
            qf[ks] = f.v;
        }
    }

    f32x16 oacc[4];
    #pragma unroll
    for (int i = 0; i < 4; ++i)
        #pragma unroll
        for (int j = 0; j < 16; ++j) oacc[i][j] = 0.0f;
    float psum = 0.0f;

    const float* kb0 = kp + (size_t)b * SLK * DD;
    const float* vb0 = vp + (size_t)b * SLK * DD;
    const size_t mrow0 = ((size_t)b * SLQ + q0) * SLK;

    // ---- prefetch registers (T14: issue-early / write-late) ----
    f32x4v kreg[8];
    float  vreg[32];
    u32x4  mreg[2];

    const int vd  = tid & 127;       // d-row this thread stages for V^T
    const int vkh = tid >> 7;        // key half (0: keys 0-31, 1: keys 32-63)
    const int mqq = tid >> 1;        // mask q row
    const int mh  = tid & 1;         // mask key half
    const int swv = (vd & 7) << 4;   // V^T 16B-granular XOR (R18 change)

    #define LOAD_TILE(KB)                                                         \
        do {                                                                      \
            const int k0_ = (KB) * KVB;                                           \
            const float* kbase_ = kb0 + (size_t)k0_ * DD;                         \
            _Pragma("unroll")                                                     \
            for (int j = 0; j < 8; ++j)                                           \
                kreg[j] = *(const f32x4v*)(kbase_ + (j * 256 + tid) * 4);         \
            const float* vcol_ = vb0 + ((size_t)k0_ + 32 * vkh) * DD + vd;        \
            _Pragma("unroll")                                                     \
            for (int jj = 0; jj < 32; ++jj) vreg[jj] = vcol_[(size_t)jj * DD];    \
            if (mmode == 0) {                                                     \
                const uint8_t* ms_ = (const uint8_t*)mp + mrow0 +                 \
                                     (size_t)mqq * SLK + k0_ + mh * 32;           \
                mreg[0] = *(const u32x4*)(ms_);                                   \
                mreg[1] = *(const u32x4*)(ms_ + 16);                              \
            }                                                                     \
        } while (0)

    #define WRITE_LDS(KB)                                                         \
        do {                                                                      \
            _Pragma("unroll")                                                     \
            for (int j = 0; j < 8; ++j) {                                         \
                const int flat = (j * 256 + tid) * 4;                             \
                const int kk   = flat >> 7;                                       \
                const int dd2  = (flat & 127) * 2;                                \
                u32x2 w2;                                                         \
                w2.x = cvtpk(kreg[j].x, kreg[j].y);                               \
                w2.y = cvtpk(kreg[j].z, kreg[j].w);                               \
                *(u32x2*)((char*)k_lds + kk * 256 + (dd2 ^ ((kk & 7) << 4))) = w2;\
            }                                                                     \
            {                                                                     \
                char* vrow_ = (char*)vt_lds + vd * 128;                           \
                _Pragma("unroll")                                                 \
                for (int j = 0; j < 4; ++j) {                                     \
                    u32x4 w4;                                                     \
                    w4.x = cvtpk(vreg[8 * j + 0], vreg[8 * j + 1]);               \
                    w4.y = cvtpk(vreg[8 * j + 2], vreg[8 * j + 3]);               \
                    w4.z = cvtpk(vreg[8 * j + 4], vreg[8 * j + 5]);               \
                    w4.w = cvtpk(vreg[8 * j + 6], vreg[8 * j + 7]);               \
                    *(u32x4*)(vrow_ + ((vkh * 64 + 16 * j) ^ swv)) = w4;          \
                }                                                                 \
            }                                                                     \
            if (mmode == 0) {                                                     \
                m_lds[mqq * 2 + mh] = pack16(mreg[0]) | (pack16(mreg[1]) << 16);  \
            } else {                                                              \
                const size_t e0_ = mrow0 + (size_t)mqq * SLK + (KB) * KVB + mh * 32; \
                uint32_t bits = 0;                                                \
                if (mmode == 1) {                                                 \
                    const uint32_t* s_ = (const uint32_t*)mp + e0_;               \
                    for (int j = 0; j < 32; ++j) bits |= (s_[j] ? 1u : 0u) << j;  \
                } else {                                                          \
                    const uint64_t* s_ = (const uint64_t*)mp + e0_;               \
                    for (int j = 0; j < 32; ++j) bits |= (s_[j] ? 1u : 0u) << j;  \
                }                                                                 \
                m_lds[mqq * 2 + mh] = bits;                                       \
            }                                                                     \
        } while (0)

    LOAD_TILE(0);

    for (int kb = 0; kb < NKB; ++kb) {
        // ---- write LDS from prefetch regs; vmcnt wait lands HERE, pinned by
        //      the barrier structure (a full compute phase has hidden the loads)
        WRITE_LDS(kb);
        __syncthreads();

        // ---- issue next tile's loads, pinned above compute ----
        if (kb + 1 < NKB) LOAD_TILE(kb + 1);
        __builtin_amdgcn_sched_barrier(0);

        // ---- swapped QK^T: sacc[t] = S^T (keys 32t.. x 32 q), log2 units ----
        f32x16 sacc[2];
        #pragma unroll
        for (int t = 0; t < 2; ++t)
            #pragma unroll
            for (int j = 0; j < 16; ++j) sacc[t][j] = 0.0f;
        __builtin_amdgcn_s_setprio(1);
        #pragma unroll
        for (int t = 0; t < 2; ++t) {
            const int row = 32 * t + l31;
            const char* krow = (const char*)k_lds + row * 256;
            const int sw = (row & 7) << 4;
            #pragma unroll
            for (int ks = 0; ks < 8; ++ks) {
                bf16x8 af = *(const bf16x8*)(krow + ((32 * ks + 16 * hi2) ^ sw));
                sacc[t] = __builtin_amdgcn_mfma_f32_32x32x16_bf16(af, qf[ks], sacc[t], 0, 0, 0);
            }
        }
        __builtin_amdgcn_s_setprio(0);

        // ---- softmax: p = exp2(s'), mask via bit tile, f32 row-sum, pack bf16 ----
        const u32x2 mq = *(const u32x2*)(&m_lds[(32 * wv + l31) * 2]);
        uint32_t pw[2][8];
        #pragma unroll
        for (int t = 0; t < 2; ++t) {
            #pragma unroll
            for (int rr = 0; rr < 4; ++rr) {
                const uint32_t mn = ((t ? mq.y : mq.x) >> (8 * rr + 4 * hi2)) & 0xFu;
                float em[4];
                #pragma unroll
                for (int c = 0; c < 4; ++c) {
                    const float e = EXP2(sacc[t][4 * rr + c]);
                    em[c] = ((mn >> c) & 1u) ? 0.0f : e;
                }
                psum += (em[0] + em[1]) + (em[2] + em[3]);
                pw[t][2 * rr]     = cvtpk(em[0], em[1]);
                pw[t][2 * rr + 1] = cvtpk(em[2], em[3]);
            }
        }

        // ---- PV: O[32q x 128d] += P[32x64] * V[64x128], b128 V reads ----
        #pragma unroll
        for (int t = 0; t < 2; ++t) {
            #pragma unroll
            for (int kss = 0; kss < 2; ++kss) {
                uint32_t a0 = pw[t][4 * kss + 0], b0 = pw[t][4 * kss + 2];
                uint32_t a1 = pw[t][4 * kss + 1], b1 = pw[t][4 * kss + 3];
                perm32swap(a0, b0);
                perm32swap(a1, b1);
                FragU af;
                af.u[0] = a0; af.u[1] = a1; af.u[2] = b0; af.u[3] = b1;
                const int keyb = 64 * t + 32 * kss + 16 * hi2;  // multiple of 16
                __builtin_amdgcn_s_setprio(1);
                #pragma unroll
                for (int dt = 0; dt < 4; ++dt) {
                    const int drow = 32 * dt + l31;
                    const char* vrow = (const char*)vt_lds + drow * 128;
                    bf16x8 vf = *(const bf16x8*)(vrow + (keyb ^ ((drow & 7) << 4)));
                    oacc[dt] = __builtin_amdgcn_mfma_f32_32x32x16_bf16(af.v, vf, oacc[dt], 0, 0, 0);
                }
                __builtin_amdgcn_s_setprio(0);
            }
        }
        __syncthreads();
    }

    // ---- epilogue: combine halves of row-sums, normalize, store fp32 ----
    psum += __shfl_xor(psum, 32);
    float* obase = op + ((size_t)b * SLQ + (size_t)(q0 + 32 * wv)) * DD + l31;
    #pragma unroll
    for (int r = 0; r < 16; ++r) {
        const int qrow = (r & 3) + 8 * (r >> 2) + 4 * hi2;
        const float s  = __shfl(psum, qrow);
        const float rs = 1.0f / s;
        #pragma unroll
        for (int dt = 0; dt < 4; ++dt) {
            obase[(size_t)qrow * DD + 32 * dt] = oacc[dt][r] * rs;
        }
    }
}

extern "C" void kernel_launch(void* const* d_in, const int* in_sizes, int n_in,
                              void* d_out, int out_size, void* d_ws, size_t ws_size,
                              hipStream_t stream)
{
    const float* q = (const float*)d_in[0];
    const float* k = (const float*)d_in[1];
    const float* v = (const float*)d_in[2];
    const void*  m = d_in[3];
    float*       o = (float*)d_out;
    hipLaunchKernelGGL(attn_fwd, dim3((NB * SLQ) / QTILE), dim3(256), 0, stream,
                       q, k, v, m, o);
}